// Round 12
// baseline (401.225 us; speedup 1.0000x reference)
//
#include <hip/hip_runtime.h>
#include <hip/hip_fp16.h>

// ---------------------------------------------------------------------------
// StrongFormPhysicsLoss, round 12: embed the linked-list head word INSIDE the
// fp16 pack row (u6 of the 32B record) so the per-endpoint atomicExch and the
// 32B node gather hit the SAME line -> L2/MSHR merges the fetch (~halves
// distinct scattered line fetches in elem_ll). Drops the 4MB head array.
//   K1 pack_nodes : [N] 32B fp16 node rows, u6=head(=ENDTAG), u7=0
//   K2 elem_ll    : ILP=4; atomicExch on pack[8k+6] + same-line gather
//   K3 node_ll    : ILP=4 chain chase; head read = pack[8k+6] (strided)
//   K4 finalize
// ---------------------------------------------------------------------------

typedef __attribute__((ext_vector_type(4))) float    f4;
typedef __attribute__((ext_vector_type(4))) unsigned u4;
typedef __attribute__((ext_vector_type(2))) int      i2;

#define ILP 4
#define ENDTAG 0xFFFFFFFFu

struct Scal {
    double rkin2, e1, e2, Lsum;
    double Fe2, F2, Mr2, Mp2;
    unsigned int qmax_bits, Lmax_bits;
    unsigned int cnt_d, cnt_r, cnt_p;
};

__device__ __forceinline__ unsigned pkh(float a, float b) {
    __half2 h = __floats2half2_rn(a, b);
    return *reinterpret_cast<unsigned*>(&h);
}
__device__ __forceinline__ float2 unpkh(unsigned u) {
    __half2 h = *reinterpret_cast<__half2*>(&u);
    return __half22float2(h);
}

__device__ __forceinline__ double waveSumD(double v) {
#pragma unroll
    for (int o = 32; o > 0; o >>= 1) v += __shfl_down(v, o, 64);
    return v;
}
__device__ __forceinline__ float waveMaxF(float v) {
#pragma unroll
    for (int o = 32; o > 0; o >>= 1) v = fmaxf(v, __shfl_down(v, o, 64));
    return v;
}
__device__ __forceinline__ unsigned waveSumU(unsigned v) {
#pragma unroll
    for (int o = 32; o > 0; o >>= 1) v += __shfl_down(v, o, 64);
    return v;
}

__device__ __forceinline__ void blockAtomicAddD(double v, double* dst, double* smem) {
    v = waveSumD(v);
    const int lane = threadIdx.x & 63, wid = threadIdx.x >> 6;
    if (lane == 0) smem[wid] = v;
    __syncthreads();
    if (threadIdx.x == 0) atomicAdd(dst, smem[0] + smem[1] + smem[2] + smem[3]);
    __syncthreads();
}
__device__ __forceinline__ void blockAtomicMaxF(float v, unsigned int* dst, float* smem) {
    v = waveMaxF(v);
    const int lane = threadIdx.x & 63, wid = threadIdx.x >> 6;
    if (lane == 0) smem[wid] = v;
    __syncthreads();
    if (threadIdx.x == 0) {
        float r = fmaxf(fmaxf(smem[0], smem[1]), fmaxf(smem[2], smem[3]));
        atomicMax(dst, __float_as_uint(fmaxf(r, 0.0f)));
    }
    __syncthreads();
}
__device__ __forceinline__ void blockAtomicAddU(unsigned v, unsigned int* dst, unsigned* smem) {
    v = waveSumU(v);
    const int lane = threadIdx.x & 63, wid = threadIdx.x >> 6;
    if (lane == 0) smem[wid] = v;
    __syncthreads();
    if (threadIdx.x == 0) atomicAdd(dst, smem[0] + smem[1] + smem[2] + smem[3]);
    __syncthreads();
}

// ---------------------------------------------------------------------------
// fp16 pack row (32B = 8 u32): u0=(ux,uz) u1=(phi,gux0) u2=(gux1,gux2)
//   u3=(guz0,guz1) u4=(guz2,gphi0) u5=(gphi1,gphi2) u6=HEAD u7=0
__global__ __launch_bounds__(256) void pack_nodes(
    const float* __restrict__ pred, const float* __restrict__ gux,
    const float* __restrict__ guz,  const float* __restrict__ gphi,
    unsigned* __restrict__ pack, int n)
{
    const int k = blockIdx.x * blockDim.x + threadIdx.x;
    if (k >= n) return;
    const size_t b3 = 3 * (size_t)k;
    const float p0 = __builtin_nontemporal_load(pred + b3);
    const float p1 = __builtin_nontemporal_load(pred + b3 + 1);
    const float p2 = __builtin_nontemporal_load(pred + b3 + 2);
    const float a0 = __builtin_nontemporal_load(gux + b3);
    const float a1 = __builtin_nontemporal_load(gux + b3 + 1);
    const float a2 = __builtin_nontemporal_load(gux + b3 + 2);
    const float z0 = __builtin_nontemporal_load(guz + b3);
    const float z1 = __builtin_nontemporal_load(guz + b3 + 1);
    const float z2 = __builtin_nontemporal_load(guz + b3 + 2);
    const float f0 = __builtin_nontemporal_load(gphi + b3);
    const float f1 = __builtin_nontemporal_load(gphi + b3 + 1);
    const float f2 = __builtin_nontemporal_load(gphi + b3 + 2);

    u4* o = (u4*)(pack + 8 * (size_t)k);
    o[0] = (u4){pkh(p0, p1), pkh(p2, a0), pkh(a1, a2), pkh(z0, z1)};
    o[1] = (u4){pkh(z2, f0), pkh(f1, f2), ENDTAG, 0u};
}

// ---------------------------------------------------------------------------
struct NodeG { f4 a, b, c; };

__device__ __forceinline__ NodeG decode_pack(const u4& q0, const u4& q1) {
    const float2 uu = unpkh(q0.x), pg = unpkh(q0.y), g12 = unpkh(q0.z);
    const float2 zz = unpkh(q0.w), zp = unpkh(q1.x), pp = unpkh(q1.y);
    NodeG g;
    g.a = (f4){uu.x, uu.y, pg.x, pg.y};
    g.b = (f4){g12.x, g12.y, zz.x, zz.y};
    g.c = (f4){zp.x, zp.y, pp.x, pp.y};
    return g;
}
__device__ __forceinline__ NodeG gather_node_raw(
    const float* __restrict__ pred, const float* __restrict__ gux,
    const float* __restrict__ guz,  const float* __restrict__ gphi, int k) {
    const size_t b3 = 3 * (size_t)k;
    NodeG g;
    g.a = (f4){pred[b3], pred[b3+1], pred[b3+2], gux[b3]};
    g.b = (f4){gux[b3+1], gux[b3+2], guz[b3], guz[b3+1]};
    g.c = (f4){guz[b3+2], gphi[b3], gphi[b3+1], gphi[b3+2]};
    return g;
}

struct ElemOut {
    float Fe0, Fe1, Fe2, Mi0, Mi1, Mi2, Mj0, Mj1, Mj2, E0, E1, E2;
    float rkin, d1, d2, Le, l0, l1, l2;
};

__device__ __forceinline__ ElemOut physics(
    const NodeG& ni, const NodeG& nj,
    float x0, float x1, float x2,
    float Le, float EA, float EI,
    float l0, float l1, float l2)
{
    const bool par = fabsf(x1) > 0.99f;
    float z0, z1, z2;
    if (par) { z0 = x1; z1 = -x0; z2 = 0.0f; }
    else     { z0 = -x2; z1 = 0.0f; z2 = x0; }
    float zn = fmaxf(sqrtf(z0 * z0 + z1 * z1 + z2 * z2), 1e-8f);
    z0 /= zn; z1 /= zn; z2 /= zn;
    float y0 = z1 * x2 - z2 * x1;
    float y1 = z2 * x0 - z0 * x2;
    float y2 = z0 * x1 - z1 * x0;
    float yn = fmaxf(sqrtf(y0 * y0 + y1 * y1 + y2 * y2), 1e-8f);
    y0 /= yn; y1 /= yn; y2 /= yn;

    const float uxi = ni.a.x, uzi = ni.a.y, phii = ni.a.z;
    const float uxj = nj.a.x, uzj = nj.a.y, phij = nj.a.z;
    const float gxi   = ni.a.w * x0 + ni.b.x * x1 + ni.b.y * x2;
    const float gzi   = ni.b.z * x0 + ni.b.w * x1 + ni.c.x * x2;
    const float kap_i = ni.c.y * x0 + ni.c.z * x1 + ni.c.w * x2;
    const float gxj   = nj.a.w * x0 + nj.b.x * x1 + nj.b.y * x2;
    const float gzj   = nj.b.z * x0 + nj.b.w * x1 + nj.c.x * x2;
    const float kap_j = nj.c.y * x0 + nj.c.z * x1 + nj.c.w * x2;

    const float dux = uxj - uxi, duz = uzj - uzi;
    const float invL = 1.0f / Le;

    const float du_ax  = dux * x0 + duz * x2;
    const float eps_fd = du_ax * invL;
    const float N_fd   = EA * eps_fd;
    const float du_tr  = dux * z0 + duz * z2;
    const float kappa_fd = (phij - phii) * invL;

    const float EIL = EI * invL, EIL2 = EIL * invL, EIL3 = EIL2 * invL;
    const float V_fd = 12.0f * EIL3 * du_tr - 6.0f * EIL2 * (phii + phij);
    const float M_yi = 6.0f * EIL2 * du_tr - EIL * (4.0f * phii + 2.0f * phij);
    const float M_yj = 6.0f * EIL2 * du_tr - EIL * (2.0f * phii + 4.0f * phij);

    const float eps_ag   = 0.5f * ((x0 * gxi + x2 * gzi) + (x0 * gxj + x2 * gzj));
    const float kappa_ag = 0.5f * (kap_i + kap_j);
    const float hl = 0.5f * Le;

    ElemOut o;
    o.Fe0 = N_fd * x0 + V_fd * z0;
    o.Fe1 = N_fd * x1 + V_fd * z1;
    o.Fe2 = N_fd * x2 + V_fd * z2;
    o.Mi0 = M_yi * y0; o.Mi1 = M_yi * y1; o.Mi2 = M_yi * y2;
    o.Mj0 = M_yj * y0; o.Mj1 = M_yj * y1; o.Mj2 = M_yj * y2;
    o.E0 = l0 * hl; o.E1 = l1 * hl; o.E2 = l2 * hl;
    o.rkin = 0.5f * (phii + phij) - du_tr * invL;
    o.d1 = eps_ag - eps_fd;
    o.d2 = kappa_ag - kappa_fd;
    o.Le = Le; o.l0 = l0; o.l1 = l1; o.l2 = l2;
    return o;
}

__device__ __forceinline__ void elem_reduce_tail(
    const ElemOut& o, double& s_rkin2, double& s_e1, double& s_e2,
    double& s_Lsum, float& m_q, float& m_L)
{
    s_rkin2 += (double)(o.rkin * o.rkin);
    s_e1 += (double)(o.d1 * o.d1);
    s_e2 += (double)(o.d2 * o.d2);
    s_Lsum += (double)o.Le;
    m_q = fmaxf(m_q, fmaxf(fabsf(o.l0), fmaxf(fabsf(o.l1), fabsf(o.l2))));
    m_L = fmaxf(m_L, o.Le);
}

// ---------------------------------------------------------------------------
// fp16 payload record (32B = 8 u32):
//   u0=(Fe0,Fe1) u1=(Fe2,Mi0) u2=(Mi1,Mi2) u3=(Mj0,Mj1)
//   u4=(Mj2,E0)  u5=(E1,E2)   u6=next_i    u7=next_j
// PACKED: head embedded in pack row (pack[8k+6]); else separate head array.
template <bool PACKED>
__global__ __launch_bounds__(256) void elem_ll(
    const float* __restrict__ pred, const float* __restrict__ grad_ux,
    const float* __restrict__ grad_uz, const float* __restrict__ grad_phi,
    unsigned* __restrict__ pack,
    const float* __restrict__ prop_E, const float* __restrict__ prop_A,
    const float* __restrict__ prop_I22, const float* __restrict__ elemL,
    const float* __restrict__ dirs, const float* __restrict__ load,
    const int* __restrict__ conn,
    unsigned* __restrict__ payload,
    unsigned int* __restrict__ head,
    Scal* sc, int n_elems)
{
    __shared__ double smD[4];
    __shared__ float  smF[4];

    double s_rkin2 = 0.0, s_e1 = 0.0, s_e2 = 0.0, s_Lsum = 0.0;
    float m_q = 0.0f, m_L = 0.0f;

    int  e[ILP];
    bool v[ILP];
    int  ii[ILP], jj[ILP];
    unsigned nx_i[ILP], nx_j[ILP];

#pragma unroll
    for (int c = 0; c < ILP; ++c) {
        e[c] = blockIdx.x * (256 * ILP) + c * 256 + threadIdx.x;
        v[c] = e[c] < n_elems;
        ii[c] = 0; jj[c] = 0; nx_i[c] = ENDTAG; nx_j[c] = ENDTAG;
    }

#pragma unroll
    for (int c = 0; c < ILP; ++c)
        if (v[c]) { const i2 ij = __builtin_nontemporal_load((const i2*)conn + e[c]); ii[c] = ij.x; jj[c] = ij.y; }

    // 1 info-carrying atomicExch per endpoint; PACKED: targets the SAME 32B
    // chunk as the node gather below -> MSHR/L2 merge of the line fetch
#pragma unroll
    for (int c = 0; c < ILP; ++c)
        if (v[c]) {
            unsigned* hi = PACKED ? &pack[8 * (size_t)ii[c] + 6] : &head[ii[c]];
            unsigned* hj = PACKED ? &pack[8 * (size_t)jj[c] + 6] : &head[jj[c]];
            nx_i[c] = __hip_atomic_exchange(hi, ((unsigned)e[c] << 1),
                                            __ATOMIC_RELAXED, __HIP_MEMORY_SCOPE_AGENT);
            nx_j[c] = __hip_atomic_exchange(hj, ((unsigned)e[c] << 1) | 1u,
                                            __ATOMIC_RELAXED, __HIP_MEMORY_SCOPE_AGENT);
        }

    // node gathers (same lines as the exchanges when PACKED)
    NodeG ni[ILP], nj[ILP];
#pragma unroll
    for (int c = 0; c < ILP; ++c)
        if (v[c]) {
            if (PACKED) {
                const u4* pi = (const u4*)(pack + 8 * (size_t)ii[c]);
                const u4* pj = (const u4*)(pack + 8 * (size_t)jj[c]);
                const u4 qi0 = pi[0], qi1 = pi[1];   // qi1.z = head word, ignored
                const u4 qj0 = pj[0], qj1 = pj[1];
                ni[c] = decode_pack(qi0, qi1);
                nj[c] = decode_pack(qj0, qj1);
            } else {
                ni[c] = gather_node_raw(pred, grad_ux, grad_uz, grad_phi, ii[c]);
                nj[c] = gather_node_raw(pred, grad_ux, grad_uz, grad_phi, jj[c]);
            }
        }

#pragma unroll
    for (int c = 0; c < ILP; ++c)
        if (v[c]) {
            const int ec = e[c];
            const float x0 = __builtin_nontemporal_load(dirs + 3 * ec);
            const float x1 = __builtin_nontemporal_load(dirs + 3 * ec + 1);
            const float x2 = __builtin_nontemporal_load(dirs + 3 * ec + 2);
            const float Le = __builtin_nontemporal_load(elemL + ec);
            const float pE = __builtin_nontemporal_load(prop_E + ec);
            const float EA = pE * __builtin_nontemporal_load(prop_A + ec);
            const float EI = pE * __builtin_nontemporal_load(prop_I22 + ec);
            const float l0 = __builtin_nontemporal_load(load + 3 * ec);
            const float l1 = __builtin_nontemporal_load(load + 3 * ec + 1);
            const float l2 = __builtin_nontemporal_load(load + 3 * ec + 2);
            const ElemOut o = physics(ni[c], nj[c], x0, x1, x2, Le, EA, EI, l0, l1, l2);

            u4* pw = (u4*)(payload + 8 * (size_t)ec);
            pw[0] = (u4){pkh(o.Fe0, o.Fe1), pkh(o.Fe2, o.Mi0),
                         pkh(o.Mi1, o.Mi2), pkh(o.Mj0, o.Mj1)};
            pw[1] = (u4){pkh(o.Mj2, o.E0), pkh(o.E1, o.E2), nx_i[c], nx_j[c]};

            elem_reduce_tail(o, s_rkin2, s_e1, s_e2, s_Lsum, m_q, m_L);
        }

    blockAtomicAddD(s_rkin2, &sc->rkin2, smD);
    blockAtomicAddD(s_e1,    &sc->e1,    smD);
    blockAtomicAddD(s_e2,    &sc->e2,    smD);
    blockAtomicAddD(s_Lsum,  &sc->Lsum,  smD);
    blockAtomicMaxF(m_q, &sc->qmax_bits, smF);
    blockAtomicMaxF(m_L, &sc->Lmax_bits, smF);
}

// ---------------------------------------------------------------------------
struct NodeAcc { float F0, F1, F2, M0, M1, M2, E0, E1, E2; };

template <bool PACKED>
__global__ __launch_bounds__(256) void node_ll(
    const unsigned* __restrict__ payload,
    const unsigned* __restrict__ pack,
    const unsigned int* __restrict__ head,
    const float* __restrict__ bc_disp, const float* __restrict__ bc_rot,
    Scal* sc, int n_nodes)
{
    __shared__ double smD[4];
    __shared__ unsigned smU[4];

    double sFe2 = 0.0, sF2 = 0.0, sMr2 = 0.0, sMp2 = 0.0;
    unsigned cd = 0, cr = 0, cp = 0;

    int  k[ILP];
    bool fd[ILP], fr[ILP], pin[ILP];
    unsigned cur[ILP];
    NodeAcc A[ILP];

#pragma unroll
    for (int c = 0; c < ILP; ++c) {
        k[c] = blockIdx.x * (256 * ILP) + c * 256 + threadIdx.x;
        const bool vc = k[c] < n_nodes;
        float bd = 1.f, br = 1.f;
        if (vc) { bd = bc_disp[k[c]]; br = bc_rot[k[c]]; }
        fd[c] = vc && (bd < 0.5f);
        fr[c] = vc && (br < 0.5f);
        pin[c] = vc && (bd > 0.5f) && fr[c];
        cur[c] = ENDTAG;
        if (fd[c] | fr[c])
            cur[c] = PACKED ? pack[8 * (size_t)k[c] + 6] : head[k[c]];
        A[c] = (NodeAcc){0,0,0,0,0,0,0,0,0};
    }

    // chase: up to ILP independent chains in flight per thread
    while (true) {
        bool any = false;
#pragma unroll
        for (int c = 0; c < ILP; ++c) any |= (cur[c] != ENDTAG);
        if (!any) break;

        u4 q0[ILP], q1[ILP];
#pragma unroll
        for (int c = 0; c < ILP; ++c)
            if (cur[c] != ENDTAG) {
                const u4* p = (const u4*)(payload + 8 * (size_t)(cur[c] >> 1));
                q0[c] = p[0]; q1[c] = p[1];
            }
#pragma unroll
        for (int c = 0; c < ILP; ++c)
            if (cur[c] != ENDTAG) {
                const bool side_j = cur[c] & 1u;
                const float2 Fe01 = unpkh(q0[c].x), Fe2Mi0 = unpkh(q0[c].y);
                const float2 Mi12 = unpkh(q0[c].z), Mj01 = unpkh(q0[c].w);
                const float2 Mj2E0 = unpkh(q1[c].x), E12 = unpkh(q1[c].y);
                const float sgn = side_j ? -1.0f : 1.0f;
                A[c].F0 += sgn * Fe01.x; A[c].F1 += sgn * Fe01.y; A[c].F2 += sgn * Fe2Mi0.x;
                if (side_j) { A[c].M0 += Mj01.x;   A[c].M1 += Mj01.y; A[c].M2 += Mj2E0.x; }
                else        { A[c].M0 += Fe2Mi0.y; A[c].M1 += Mi12.x; A[c].M2 += Mi12.y; }
                A[c].E0 += Mj2E0.y; A[c].E1 += E12.x; A[c].E2 += E12.y;
                cur[c] = side_j ? q1[c].w : q1[c].z;
            }
    }

#pragma unroll
    for (int c = 0; c < ILP; ++c) {
        if (fd[c]) {
            const float f0 = A[c].F0 + A[c].E0, f1 = A[c].F1 + A[c].E1, f2 = A[c].F2 + A[c].E2;
            sFe2 += (double)(A[c].E0 * A[c].E0 + A[c].E1 * A[c].E1 + A[c].E2 * A[c].E2);
            sF2  += (double)(f0 * f0 + f1 * f1 + f2 * f2);
            cd++;
        }
        const double mm = (double)(A[c].M0 * A[c].M0 + A[c].M1 * A[c].M1 + A[c].M2 * A[c].M2);
        if (fr[c])  { sMr2 += mm; cr++; }
        if (pin[c]) { sMp2 += mm; cp++; }
    }

    blockAtomicAddD(sFe2, &sc->Fe2, smD);
    blockAtomicAddD(sF2,  &sc->F2,  smD);
    blockAtomicAddD(sMr2, &sc->Mr2, smD);
    blockAtomicAddD(sMp2, &sc->Mp2, smD);
    blockAtomicAddU(cd, &sc->cnt_d, smU);
    blockAtomicAddU(cr, &sc->cnt_r, smU);
    blockAtomicAddU(cp, &sc->cnt_p, smU);
}

// --- last-resort fallback: R1-style SoA atomics ----------------------------
__global__ __launch_bounds__(256) void elem_soa(
    const float* __restrict__ pred, const float* __restrict__ grad_ux,
    const float* __restrict__ grad_uz, const float* __restrict__ grad_phi,
    const float* __restrict__ prop_E, const float* __restrict__ prop_A,
    const float* __restrict__ prop_I22, const float* __restrict__ elemL,
    const float* __restrict__ dirs, const float* __restrict__ load,
    const int* __restrict__ conn,
    float* __restrict__ Fi, float* __restrict__ Mi, float* __restrict__ Fe,
    Scal* sc, int n_elems)
{
    __shared__ double smD[4];
    __shared__ float  smF[4];
    double s_rkin2 = 0.0, s_e1 = 0.0, s_e2 = 0.0, s_Lsum = 0.0;
    float m_q = 0.0f, m_L = 0.0f;

    const int e = blockIdx.x * 256 + threadIdx.x;
    if (e < n_elems) {
        const i2 ij = __builtin_nontemporal_load((const i2*)conn + e);
        const int i = ij.x, j = ij.y;
        const NodeG ni = gather_node_raw(pred, grad_ux, grad_uz, grad_phi, i);
        const NodeG nj = gather_node_raw(pred, grad_ux, grad_uz, grad_phi, j);
        const float x0 = dirs[3 * e], x1 = dirs[3 * e + 1], x2 = dirs[3 * e + 2];
        const float Le = elemL[e];
        const float pE = prop_E[e];
        const float EA = pE * prop_A[e];
        const float EI = pE * prop_I22[e];
        const float l0 = load[3 * e], l1 = load[3 * e + 1], l2 = load[3 * e + 2];
        const ElemOut o = physics(ni, nj, x0, x1, x2, Le, EA, EI, l0, l1, l2);
        atomicAdd(&Fi[3 * i], o.Fe0);  atomicAdd(&Fi[3 * i + 1], o.Fe1);  atomicAdd(&Fi[3 * i + 2], o.Fe2);
        atomicAdd(&Fi[3 * j], -o.Fe0); atomicAdd(&Fi[3 * j + 1], -o.Fe1); atomicAdd(&Fi[3 * j + 2], -o.Fe2);
        atomicAdd(&Mi[3 * i], o.Mi0);  atomicAdd(&Mi[3 * i + 1], o.Mi1);  atomicAdd(&Mi[3 * i + 2], o.Mi2);
        atomicAdd(&Mi[3 * j], o.Mj0);  atomicAdd(&Mi[3 * j + 1], o.Mj1);  atomicAdd(&Mi[3 * j + 2], o.Mj2);
        atomicAdd(&Fe[3 * i], o.E0);   atomicAdd(&Fe[3 * i + 1], o.E1);   atomicAdd(&Fe[3 * i + 2], o.E2);
        atomicAdd(&Fe[3 * j], o.E0);   atomicAdd(&Fe[3 * j + 1], o.E1);   atomicAdd(&Fe[3 * j + 2], o.E2);
        elem_reduce_tail(o, s_rkin2, s_e1, s_e2, s_Lsum, m_q, m_L);
    }
    blockAtomicAddD(s_rkin2, &sc->rkin2, smD);
    blockAtomicAddD(s_e1,    &sc->e1,    smD);
    blockAtomicAddD(s_e2,    &sc->e2,    smD);
    blockAtomicAddD(s_Lsum,  &sc->Lsum,  smD);
    blockAtomicMaxF(m_q, &sc->qmax_bits, smF);
    blockAtomicMaxF(m_L, &sc->Lmax_bits, smF);
}

__global__ __launch_bounds__(256) void node_soa(
    const float* __restrict__ Fi, const float* __restrict__ Mi, const float* __restrict__ Fe,
    const float* __restrict__ bc_disp, const float* __restrict__ bc_rot,
    Scal* sc, int n_nodes)
{
    __shared__ double smD[4];
    __shared__ unsigned smU[4];
    double sFe2 = 0.0, sF2 = 0.0, sMr2 = 0.0, sMp2 = 0.0;
    unsigned cd = 0, cr = 0, cp = 0;

    const int k = blockIdx.x * 256 + threadIdx.x;
    if (k < n_nodes) {
        const float bd = bc_disp[k], br = bc_rot[k];
        const bool free_d = bd < 0.5f;
        const bool free_r = br < 0.5f;
        const bool pin    = (bd > 0.5f) && free_r;
        if (free_d) {
            const float e0 = Fe[3 * k], e1 = Fe[3 * k + 1], e2 = Fe[3 * k + 2];
            const float f0 = Fi[3 * k] + e0, f1 = Fi[3 * k + 1] + e1, f2 = Fi[3 * k + 2] + e2;
            sFe2 += (double)(e0 * e0 + e1 * e1 + e2 * e2);
            sF2  += (double)(f0 * f0 + f1 * f1 + f2 * f2);
            cd++;
        }
        if (free_r | pin) {
            const float m0 = Mi[3 * k], m1 = Mi[3 * k + 1], m2 = Mi[3 * k + 2];
            const double mm = (double)(m0 * m0 + m1 * m1 + m2 * m2);
            if (free_r) { sMr2 += mm; cr++; }
            if (pin)    { sMp2 += mm; cp++; }
        }
    }
    blockAtomicAddD(sFe2, &sc->Fe2, smD);
    blockAtomicAddD(sF2,  &sc->F2,  smD);
    blockAtomicAddD(sMr2, &sc->Mr2, smD);
    blockAtomicAddD(sMp2, &sc->Mp2, smD);
    blockAtomicAddU(cd, &sc->cnt_d, smU);
    blockAtomicAddU(cr, &sc->cnt_r, smU);
    blockAtomicAddU(cp, &sc->cnt_p, smU);
}

__global__ void finalize(const Scal* sc, float* out, int n_elems)
{
    const double cnt_d = (double)max(sc->cnt_d, 1u);
    const double cnt_r = (double)max(sc->cnt_r, 1u);
    const double cnt_p = (double)max(sc->cnt_p, 1u);

    const double F_char = fmax(sqrt(sc->Fe2 / (cnt_d * 3.0)), 1.0);
    const double L_force = sc->F2 / (cnt_d * 3.0) / (F_char * F_char);

    const double qmax = fmax((double)__uint_as_float(sc->qmax_bits), 1.0);
    const double Lmax = (double)__uint_as_float(sc->Lmax_bits);
    const double M_char = fmax(qmax * Lmax * sc->Lsum / 8.0, 1.0);

    const double L_moment  = sc->Mr2 / (cnt_r * 3.0) / (M_char * M_char);
    const double L_neumann = sc->Mp2 / (cnt_p * 3.0) / (M_char * M_char);

    const double inv_ne = 1.0 / (double)n_elems;
    const double L_kin = sc->rkin2 * inv_ne;
    const double L_consist = sc->e1 * inv_ne + sc->e2 * inv_ne;

    out[0] = (float)(L_force + L_moment + L_neumann + 0.1 * L_kin + L_consist);
}

extern "C" void kernel_launch(void* const* d_in, const int* in_sizes, int n_in,
                              void* d_out, int out_size, void* d_ws, size_t ws_size,
                              hipStream_t stream)
{
    const float* pred     = (const float*)d_in[0];
    const float* grad_ux  = (const float*)d_in[1];
    const float* grad_uz  = (const float*)d_in[2];
    const float* grad_phi = (const float*)d_in[3];
    const float* prop_E   = (const float*)d_in[4];
    const float* prop_A   = (const float*)d_in[5];
    const float* prop_I22 = (const float*)d_in[6];
    const float* elemL    = (const float*)d_in[7];
    const float* dirs     = (const float*)d_in[8];
    const float* load     = (const float*)d_in[9];
    const float* bc_disp  = (const float*)d_in[10];
    const float* bc_rot   = (const float*)d_in[11];
    const int*   conn     = (const int*)d_in[12];

    const int n_elems = in_sizes[4];
    const int n_nodes = in_sizes[10];
    const int nblkN  = (n_nodes + 255) / 256;
    const int perBlk = 256 * ILP;
    const int nblkE4 = (n_elems + perBlk - 1) / perBlk;
    const int nblkN4 = (n_nodes + perBlk - 1) / perBlk;

    const size_t szPack = (size_t)n_nodes * 32;                  // 32MB fp16+head
    const size_t szPay  = (size_t)n_elems * 32;                  // 64MB fp16
    const size_t szHead = (size_t)n_nodes * sizeof(unsigned);    // 4MB (tier B)
    const size_t szTail = 256;

    char* base = (char*)d_ws;

    if (ws_size >= szPack + szPay + szTail) {
        // ---- tier A: fp16 pack w/ embedded head + linked-list (96MB) ----
        unsigned* pack    = (unsigned*)base; base += szPack;
        unsigned* payload = (unsigned*)base; base += szPay;
        Scal*     sc      = (Scal*)base;

        hipMemsetAsync(sc, 0, sizeof(Scal), stream);

        pack_nodes<<<nblkN, 256, 0, stream>>>(
            pred, grad_ux, grad_uz, grad_phi, pack, n_nodes);
        elem_ll<true><<<nblkE4, 256, 0, stream>>>(
            pred, grad_ux, grad_uz, grad_phi, pack,
            prop_E, prop_A, prop_I22, elemL, dirs, load, conn,
            payload, nullptr, sc, n_elems);
        node_ll<true><<<nblkN4, 256, 0, stream>>>(
            payload, pack, nullptr, bc_disp, bc_rot, sc, n_nodes);
        finalize<<<1, 1, 0, stream>>>(sc, (float*)d_out, n_elems);
    } else if (ws_size >= szPay + szHead + szTail) {
        // ---- tier B: fp16 linked-list, raw gathers, separate head (68MB) ----
        unsigned*     payload = (unsigned*)base;     base += szPay;
        unsigned int* head    = (unsigned int*)base; base += szHead;
        Scal*         sc      = (Scal*)base;

        hipMemsetAsync(head, 0xFF, szHead, stream);
        hipMemsetAsync(sc, 0, sizeof(Scal), stream);

        elem_ll<false><<<nblkE4, 256, 0, stream>>>(
            pred, grad_ux, grad_uz, grad_phi, nullptr,
            prop_E, prop_A, prop_I22, elemL, dirs, load, conn,
            payload, head, sc, n_elems);
        node_ll<false><<<nblkN4, 256, 0, stream>>>(
            payload, nullptr, head, bc_disp, bc_rot, sc, n_nodes);
        finalize<<<1, 1, 0, stream>>>(sc, (float*)d_out, n_elems);
    } else {
        // ---- tier C: SoA atomic fallback (36MB) ----
        float* Fi = (float*)d_ws;
        float* Mi = Fi + (size_t)3 * n_nodes;
        float* Fe = Mi + (size_t)3 * n_nodes;
        const size_t nodeBytes = (size_t)9 * n_nodes * sizeof(float);
        Scal* sc = (Scal*)((char*)d_ws + nodeBytes);

        hipMemsetAsync(d_ws, 0, nodeBytes + sizeof(Scal), stream);

        elem_soa<<<(n_elems + 255) / 256, 256, 0, stream>>>(
            pred, grad_ux, grad_uz, grad_phi,
            prop_E, prop_A, prop_I22, elemL, dirs, load, conn,
            Fi, Mi, Fe, sc, n_elems);
        node_soa<<<nblkN, 256, 0, stream>>>(
            Fi, Mi, Fe, bc_disp, bc_rot, sc, n_nodes);
        finalize<<<1, 1, 0, stream>>>(sc, (float*)d_out, n_elems);
    }
}

// Round 13
// 390.856 us; speedup vs baseline: 1.0265x; 1.0265x over previous
//
#include <hip/hip_runtime.h>
#include <hip/hip_fp16.h>

// ---------------------------------------------------------------------------
// StrongFormPhysicsLoss, FINAL (revert to round-11 best: 389us).
// Structure: fp16 L3-resident working set + atomicExch linked-list inverse
// map (minimum scattered ops: 1 info-carrying atomic per endpoint).
//   K1 pack_nodes : [N] 32B fp16 node rows + head[k]=ENDTAG init
//   K2 elem_ll    : ILP=4 physics; 1 atomicExch per endpoint; 32B fp16
//                   payload records w/ embedded next-pointers
//   K3 node_ll    : ILP=4 chain chase over 32B records
//   K4 finalize
// Measured cost model (MI355X): scattered line-ops saturate ~34G ops/s
// (invariant to ILP/occupancy/footprint; R7-R12); elem=8M ops ~= 247us,
// node ~= 100us, pack ~= 30us -> 389us ~= 4% above modeled floor.
// R12 lesson: same-line atomic+load does NOT merge (per-op charging).
// ---------------------------------------------------------------------------

typedef __attribute__((ext_vector_type(4))) float    f4;
typedef __attribute__((ext_vector_type(4))) unsigned u4;
typedef __attribute__((ext_vector_type(2))) int      i2;

#define ILP 4
#define ENDTAG 0xFFFFFFFFu

struct Scal {
    double rkin2, e1, e2, Lsum;
    double Fe2, F2, Mr2, Mp2;
    unsigned int qmax_bits, Lmax_bits;
    unsigned int cnt_d, cnt_r, cnt_p;
};

__device__ __forceinline__ unsigned pkh(float a, float b) {
    __half2 h = __floats2half2_rn(a, b);
    return *reinterpret_cast<unsigned*>(&h);
}
__device__ __forceinline__ float2 unpkh(unsigned u) {
    __half2 h = *reinterpret_cast<__half2*>(&u);
    return __half22float2(h);
}

__device__ __forceinline__ double waveSumD(double v) {
#pragma unroll
    for (int o = 32; o > 0; o >>= 1) v += __shfl_down(v, o, 64);
    return v;
}
__device__ __forceinline__ float waveMaxF(float v) {
#pragma unroll
    for (int o = 32; o > 0; o >>= 1) v = fmaxf(v, __shfl_down(v, o, 64));
    return v;
}
__device__ __forceinline__ unsigned waveSumU(unsigned v) {
#pragma unroll
    for (int o = 32; o > 0; o >>= 1) v += __shfl_down(v, o, 64);
    return v;
}

__device__ __forceinline__ void blockAtomicAddD(double v, double* dst, double* smem) {
    v = waveSumD(v);
    const int lane = threadIdx.x & 63, wid = threadIdx.x >> 6;
    if (lane == 0) smem[wid] = v;
    __syncthreads();
    if (threadIdx.x == 0) atomicAdd(dst, smem[0] + smem[1] + smem[2] + smem[3]);
    __syncthreads();
}
__device__ __forceinline__ void blockAtomicMaxF(float v, unsigned int* dst, float* smem) {
    v = waveMaxF(v);
    const int lane = threadIdx.x & 63, wid = threadIdx.x >> 6;
    if (lane == 0) smem[wid] = v;
    __syncthreads();
    if (threadIdx.x == 0) {
        float r = fmaxf(fmaxf(smem[0], smem[1]), fmaxf(smem[2], smem[3]));
        atomicMax(dst, __float_as_uint(fmaxf(r, 0.0f)));
    }
    __syncthreads();
}
__device__ __forceinline__ void blockAtomicAddU(unsigned v, unsigned int* dst, unsigned* smem) {
    v = waveSumU(v);
    const int lane = threadIdx.x & 63, wid = threadIdx.x >> 6;
    if (lane == 0) smem[wid] = v;
    __syncthreads();
    if (threadIdx.x == 0) atomicAdd(dst, smem[0] + smem[1] + smem[2] + smem[3]);
    __syncthreads();
}

// ---------------------------------------------------------------------------
// fp16 pack row (32B = 8 u32): u0=(ux,uz) u1=(phi,gux0) u2=(gux1,gux2)
//   u3=(guz0,guz1) u4=(guz2,gphi0) u5=(gphi1,gphi2) u6,u7 pad
__global__ __launch_bounds__(256) void pack_nodes(
    const float* __restrict__ pred, const float* __restrict__ gux,
    const float* __restrict__ guz,  const float* __restrict__ gphi,
    unsigned* __restrict__ pack, unsigned* __restrict__ head, int n)
{
    const int k = blockIdx.x * blockDim.x + threadIdx.x;
    if (k >= n) return;
    const size_t b3 = 3 * (size_t)k;
    const float p0 = __builtin_nontemporal_load(pred + b3);
    const float p1 = __builtin_nontemporal_load(pred + b3 + 1);
    const float p2 = __builtin_nontemporal_load(pred + b3 + 2);
    const float a0 = __builtin_nontemporal_load(gux + b3);
    const float a1 = __builtin_nontemporal_load(gux + b3 + 1);
    const float a2 = __builtin_nontemporal_load(gux + b3 + 2);
    const float z0 = __builtin_nontemporal_load(guz + b3);
    const float z1 = __builtin_nontemporal_load(guz + b3 + 1);
    const float z2 = __builtin_nontemporal_load(guz + b3 + 2);
    const float f0 = __builtin_nontemporal_load(gphi + b3);
    const float f1 = __builtin_nontemporal_load(gphi + b3 + 1);
    const float f2 = __builtin_nontemporal_load(gphi + b3 + 2);

    u4* o = (u4*)(pack + 8 * (size_t)k);
    o[0] = (u4){pkh(p0, p1), pkh(p2, a0), pkh(a1, a2), pkh(z0, z1)};
    o[1] = (u4){pkh(z2, f0), pkh(f1, f2), 0u, 0u};
    head[k] = ENDTAG;
}

// ---------------------------------------------------------------------------
struct NodeG { f4 a, b, c; };

__device__ __forceinline__ NodeG gather_node_h(const unsigned* __restrict__ pack, int k) {
    const u4* p = (const u4*)(pack + 8 * (size_t)k);
    const u4 q0 = p[0], q1 = p[1];
    const float2 uu = unpkh(q0.x), pg = unpkh(q0.y), g12 = unpkh(q0.z);
    const float2 zz = unpkh(q0.w), zp = unpkh(q1.x), pp = unpkh(q1.y);
    NodeG g;
    g.a = (f4){uu.x, uu.y, pg.x, pg.y};
    g.b = (f4){g12.x, g12.y, zz.x, zz.y};
    g.c = (f4){zp.x, zp.y, pp.x, pp.y};
    return g;
}
__device__ __forceinline__ NodeG gather_node_raw(
    const float* __restrict__ pred, const float* __restrict__ gux,
    const float* __restrict__ guz,  const float* __restrict__ gphi, int k) {
    const size_t b3 = 3 * (size_t)k;
    NodeG g;
    g.a = (f4){pred[b3], pred[b3+1], pred[b3+2], gux[b3]};
    g.b = (f4){gux[b3+1], gux[b3+2], guz[b3], guz[b3+1]};
    g.c = (f4){guz[b3+2], gphi[b3], gphi[b3+1], gphi[b3+2]};
    return g;
}

struct ElemOut {
    float Fe0, Fe1, Fe2, Mi0, Mi1, Mi2, Mj0, Mj1, Mj2, E0, E1, E2;
    float rkin, d1, d2, Le, l0, l1, l2;
};

__device__ __forceinline__ ElemOut physics(
    const NodeG& ni, const NodeG& nj,
    float x0, float x1, float x2,
    float Le, float EA, float EI,
    float l0, float l1, float l2)
{
    const bool par = fabsf(x1) > 0.99f;
    float z0, z1, z2;
    if (par) { z0 = x1; z1 = -x0; z2 = 0.0f; }
    else     { z0 = -x2; z1 = 0.0f; z2 = x0; }
    float zn = fmaxf(sqrtf(z0 * z0 + z1 * z1 + z2 * z2), 1e-8f);
    z0 /= zn; z1 /= zn; z2 /= zn;
    float y0 = z1 * x2 - z2 * x1;
    float y1 = z2 * x0 - z0 * x2;
    float y2 = z0 * x1 - z1 * x0;
    float yn = fmaxf(sqrtf(y0 * y0 + y1 * y1 + y2 * y2), 1e-8f);
    y0 /= yn; y1 /= yn; y2 /= yn;

    const float uxi = ni.a.x, uzi = ni.a.y, phii = ni.a.z;
    const float uxj = nj.a.x, uzj = nj.a.y, phij = nj.a.z;
    const float gxi   = ni.a.w * x0 + ni.b.x * x1 + ni.b.y * x2;
    const float gzi   = ni.b.z * x0 + ni.b.w * x1 + ni.c.x * x2;
    const float kap_i = ni.c.y * x0 + ni.c.z * x1 + ni.c.w * x2;
    const float gxj   = nj.a.w * x0 + nj.b.x * x1 + nj.b.y * x2;
    const float gzj   = nj.b.z * x0 + nj.b.w * x1 + nj.c.x * x2;
    const float kap_j = nj.c.y * x0 + nj.c.z * x1 + nj.c.w * x2;

    const float dux = uxj - uxi, duz = uzj - uzi;
    const float invL = 1.0f / Le;

    const float du_ax  = dux * x0 + duz * x2;
    const float eps_fd = du_ax * invL;
    const float N_fd   = EA * eps_fd;
    const float du_tr  = dux * z0 + duz * z2;
    const float kappa_fd = (phij - phii) * invL;

    const float EIL = EI * invL, EIL2 = EIL * invL, EIL3 = EIL2 * invL;
    const float V_fd = 12.0f * EIL3 * du_tr - 6.0f * EIL2 * (phii + phij);
    const float M_yi = 6.0f * EIL2 * du_tr - EIL * (4.0f * phii + 2.0f * phij);
    const float M_yj = 6.0f * EIL2 * du_tr - EIL * (2.0f * phii + 4.0f * phij);

    const float eps_ag   = 0.5f * ((x0 * gxi + x2 * gzi) + (x0 * gxj + x2 * gzj));
    const float kappa_ag = 0.5f * (kap_i + kap_j);
    const float hl = 0.5f * Le;

    ElemOut o;
    o.Fe0 = N_fd * x0 + V_fd * z0;
    o.Fe1 = N_fd * x1 + V_fd * z1;
    o.Fe2 = N_fd * x2 + V_fd * z2;
    o.Mi0 = M_yi * y0; o.Mi1 = M_yi * y1; o.Mi2 = M_yi * y2;
    o.Mj0 = M_yj * y0; o.Mj1 = M_yj * y1; o.Mj2 = M_yj * y2;
    o.E0 = l0 * hl; o.E1 = l1 * hl; o.E2 = l2 * hl;
    o.rkin = 0.5f * (phii + phij) - du_tr * invL;
    o.d1 = eps_ag - eps_fd;
    o.d2 = kappa_ag - kappa_fd;
    o.Le = Le; o.l0 = l0; o.l1 = l1; o.l2 = l2;
    return o;
}

__device__ __forceinline__ void elem_reduce_tail(
    const ElemOut& o, double& s_rkin2, double& s_e1, double& s_e2,
    double& s_Lsum, float& m_q, float& m_L)
{
    s_rkin2 += (double)(o.rkin * o.rkin);
    s_e1 += (double)(o.d1 * o.d1);
    s_e2 += (double)(o.d2 * o.d2);
    s_Lsum += (double)o.Le;
    m_q = fmaxf(m_q, fmaxf(fabsf(o.l0), fmaxf(fabsf(o.l1), fabsf(o.l2))));
    m_L = fmaxf(m_L, o.Le);
}

// ---------------------------------------------------------------------------
// fp16 payload record (32B = 8 u32):
//   u0=(Fe0,Fe1) u1=(Fe2,Mi0) u2=(Mi1,Mi2) u3=(Mj0,Mj1)
//   u4=(Mj2,E0)  u5=(E1,E2)   u6=next_i    u7=next_j
template <bool PACKED>
__global__ __launch_bounds__(256) void elem_ll(
    const float* __restrict__ pred, const float* __restrict__ grad_ux,
    const float* __restrict__ grad_uz, const float* __restrict__ grad_phi,
    const unsigned* __restrict__ pack,
    const float* __restrict__ prop_E, const float* __restrict__ prop_A,
    const float* __restrict__ prop_I22, const float* __restrict__ elemL,
    const float* __restrict__ dirs, const float* __restrict__ load,
    const int* __restrict__ conn,
    unsigned* __restrict__ payload,
    unsigned int* __restrict__ head,
    Scal* sc, int n_elems)
{
    __shared__ double smD[4];
    __shared__ float  smF[4];

    double s_rkin2 = 0.0, s_e1 = 0.0, s_e2 = 0.0, s_Lsum = 0.0;
    float m_q = 0.0f, m_L = 0.0f;

    int  e[ILP];
    bool v[ILP];
    int  ii[ILP], jj[ILP];
    unsigned nx_i[ILP], nx_j[ILP];

#pragma unroll
    for (int c = 0; c < ILP; ++c) {
        e[c] = blockIdx.x * (256 * ILP) + c * 256 + threadIdx.x;
        v[c] = e[c] < n_elems;
        ii[c] = 0; jj[c] = 0; nx_i[c] = ENDTAG; nx_j[c] = ENDTAG;
    }

#pragma unroll
    for (int c = 0; c < ILP; ++c)
        if (v[c]) { const i2 ij = __builtin_nontemporal_load((const i2*)conn + e[c]); ii[c] = ij.x; jj[c] = ij.y; }

    // THE scattered op: one info-carrying atomicExch per endpoint (8 in flight)
#pragma unroll
    for (int c = 0; c < ILP; ++c)
        if (v[c]) {
            nx_i[c] = __hip_atomic_exchange(&head[ii[c]], ((unsigned)e[c] << 1),
                                            __ATOMIC_RELAXED, __HIP_MEMORY_SCOPE_AGENT);
            nx_j[c] = __hip_atomic_exchange(&head[jj[c]], ((unsigned)e[c] << 1) | 1u,
                                            __ATOMIC_RELAXED, __HIP_MEMORY_SCOPE_AGENT);
        }

    // node gathers (8 lines in flight; pack is L3-resident 32MB)
    NodeG ni[ILP], nj[ILP];
#pragma unroll
    for (int c = 0; c < ILP; ++c)
        if (v[c]) {
            if (PACKED) { ni[c] = gather_node_h(pack, ii[c]); nj[c] = gather_node_h(pack, jj[c]); }
            else        { ni[c] = gather_node_raw(pred, grad_ux, grad_uz, grad_phi, ii[c]);
                          nj[c] = gather_node_raw(pred, grad_ux, grad_uz, grad_phi, jj[c]); }
        }

#pragma unroll
    for (int c = 0; c < ILP; ++c)
        if (v[c]) {
            const int ec = e[c];
            const float x0 = __builtin_nontemporal_load(dirs + 3 * ec);
            const float x1 = __builtin_nontemporal_load(dirs + 3 * ec + 1);
            const float x2 = __builtin_nontemporal_load(dirs + 3 * ec + 2);
            const float Le = __builtin_nontemporal_load(elemL + ec);
            const float pE = __builtin_nontemporal_load(prop_E + ec);
            const float EA = pE * __builtin_nontemporal_load(prop_A + ec);
            const float EI = pE * __builtin_nontemporal_load(prop_I22 + ec);
            const float l0 = __builtin_nontemporal_load(load + 3 * ec);
            const float l1 = __builtin_nontemporal_load(load + 3 * ec + 1);
            const float l2 = __builtin_nontemporal_load(load + 3 * ec + 2);
            const ElemOut o = physics(ni[c], nj[c], x0, x1, x2, Le, EA, EI, l0, l1, l2);

            // fp16 payload record: streamed, cached (node pass wants L3 hits)
            u4* pw = (u4*)(payload + 8 * (size_t)ec);
            pw[0] = (u4){pkh(o.Fe0, o.Fe1), pkh(o.Fe2, o.Mi0),
                         pkh(o.Mi1, o.Mi2), pkh(o.Mj0, o.Mj1)};
            pw[1] = (u4){pkh(o.Mj2, o.E0), pkh(o.E1, o.E2), nx_i[c], nx_j[c]};

            elem_reduce_tail(o, s_rkin2, s_e1, s_e2, s_Lsum, m_q, m_L);
        }

    blockAtomicAddD(s_rkin2, &sc->rkin2, smD);
    blockAtomicAddD(s_e1,    &sc->e1,    smD);
    blockAtomicAddD(s_e2,    &sc->e2,    smD);
    blockAtomicAddD(s_Lsum,  &sc->Lsum,  smD);
    blockAtomicMaxF(m_q, &sc->qmax_bits, smF);
    blockAtomicMaxF(m_L, &sc->Lmax_bits, smF);
}

// ---------------------------------------------------------------------------
struct NodeAcc { float F0, F1, F2, M0, M1, M2, E0, E1, E2; };

__global__ __launch_bounds__(256) void node_ll(
    const unsigned* __restrict__ payload,
    const unsigned int* __restrict__ head,
    const float* __restrict__ bc_disp, const float* __restrict__ bc_rot,
    Scal* sc, int n_nodes)
{
    __shared__ double smD[4];
    __shared__ unsigned smU[4];

    double sFe2 = 0.0, sF2 = 0.0, sMr2 = 0.0, sMp2 = 0.0;
    unsigned cd = 0, cr = 0, cp = 0;

    int  k[ILP];
    bool fd[ILP], fr[ILP], pin[ILP];
    unsigned cur[ILP];
    NodeAcc A[ILP];

#pragma unroll
    for (int c = 0; c < ILP; ++c) {
        k[c] = blockIdx.x * (256 * ILP) + c * 256 + threadIdx.x;
        const bool vc = k[c] < n_nodes;
        float bd = 1.f, br = 1.f;
        if (vc) { bd = bc_disp[k[c]]; br = bc_rot[k[c]]; }
        fd[c] = vc && (bd < 0.5f);
        fr[c] = vc && (br < 0.5f);
        pin[c] = vc && (bd > 0.5f) && fr[c];
        cur[c] = ENDTAG;
        if (fd[c] | fr[c]) cur[c] = head[k[c]];   // coalesced head read
        A[c] = (NodeAcc){0,0,0,0,0,0,0,0,0};
    }

    // chase: up to ILP independent chains in flight per thread
    while (true) {
        bool any = false;
#pragma unroll
        for (int c = 0; c < ILP; ++c) any |= (cur[c] != ENDTAG);
        if (!any) break;

        u4 q0[ILP], q1[ILP];
#pragma unroll
        for (int c = 0; c < ILP; ++c)
            if (cur[c] != ENDTAG) {
                const u4* p = (const u4*)(payload + 8 * (size_t)(cur[c] >> 1));
                q0[c] = p[0]; q1[c] = p[1];
            }
#pragma unroll
        for (int c = 0; c < ILP; ++c)
            if (cur[c] != ENDTAG) {
                const bool side_j = cur[c] & 1u;
                const float2 Fe01 = unpkh(q0[c].x), Fe2Mi0 = unpkh(q0[c].y);
                const float2 Mi12 = unpkh(q0[c].z), Mj01 = unpkh(q0[c].w);
                const float2 Mj2E0 = unpkh(q1[c].x), E12 = unpkh(q1[c].y);
                const float sgn = side_j ? -1.0f : 1.0f;
                A[c].F0 += sgn * Fe01.x; A[c].F1 += sgn * Fe01.y; A[c].F2 += sgn * Fe2Mi0.x;
                if (side_j) { A[c].M0 += Mj01.x;   A[c].M1 += Mj01.y; A[c].M2 += Mj2E0.x; }
                else        { A[c].M0 += Fe2Mi0.y; A[c].M1 += Mi12.x; A[c].M2 += Mi12.y; }
                A[c].E0 += Mj2E0.y; A[c].E1 += E12.x; A[c].E2 += E12.y;
                cur[c] = side_j ? q1[c].w : q1[c].z;
            }
    }

#pragma unroll
    for (int c = 0; c < ILP; ++c) {
        if (fd[c]) {
            const float f0 = A[c].F0 + A[c].E0, f1 = A[c].F1 + A[c].E1, f2 = A[c].F2 + A[c].E2;
            sFe2 += (double)(A[c].E0 * A[c].E0 + A[c].E1 * A[c].E1 + A[c].E2 * A[c].E2);
            sF2  += (double)(f0 * f0 + f1 * f1 + f2 * f2);
            cd++;
        }
        const double mm = (double)(A[c].M0 * A[c].M0 + A[c].M1 * A[c].M1 + A[c].M2 * A[c].M2);
        if (fr[c])  { sMr2 += mm; cr++; }
        if (pin[c]) { sMp2 += mm; cp++; }
    }

    blockAtomicAddD(sFe2, &sc->Fe2, smD);
    blockAtomicAddD(sF2,  &sc->F2,  smD);
    blockAtomicAddD(sMr2, &sc->Mr2, smD);
    blockAtomicAddD(sMp2, &sc->Mp2, smD);
    blockAtomicAddU(cd, &sc->cnt_d, smU);
    blockAtomicAddU(cr, &sc->cnt_r, smU);
    blockAtomicAddU(cp, &sc->cnt_p, smU);
}

// --- last-resort fallback: R1-style SoA atomics ----------------------------
__global__ __launch_bounds__(256) void elem_soa(
    const float* __restrict__ pred, const float* __restrict__ grad_ux,
    const float* __restrict__ grad_uz, const float* __restrict__ grad_phi,
    const float* __restrict__ prop_E, const float* __restrict__ prop_A,
    const float* __restrict__ prop_I22, const float* __restrict__ elemL,
    const float* __restrict__ dirs, const float* __restrict__ load,
    const int* __restrict__ conn,
    float* __restrict__ Fi, float* __restrict__ Mi, float* __restrict__ Fe,
    Scal* sc, int n_elems)
{
    __shared__ double smD[4];
    __shared__ float  smF[4];
    double s_rkin2 = 0.0, s_e1 = 0.0, s_e2 = 0.0, s_Lsum = 0.0;
    float m_q = 0.0f, m_L = 0.0f;

    const int e = blockIdx.x * 256 + threadIdx.x;
    if (e < n_elems) {
        const i2 ij = __builtin_nontemporal_load((const i2*)conn + e);
        const int i = ij.x, j = ij.y;
        const NodeG ni = gather_node_raw(pred, grad_ux, grad_uz, grad_phi, i);
        const NodeG nj = gather_node_raw(pred, grad_ux, grad_uz, grad_phi, j);
        const float x0 = dirs[3 * e], x1 = dirs[3 * e + 1], x2 = dirs[3 * e + 2];
        const float Le = elemL[e];
        const float pE = prop_E[e];
        const float EA = pE * prop_A[e];
        const float EI = pE * prop_I22[e];
        const float l0 = load[3 * e], l1 = load[3 * e + 1], l2 = load[3 * e + 2];
        const ElemOut o = physics(ni, nj, x0, x1, x2, Le, EA, EI, l0, l1, l2);
        atomicAdd(&Fi[3 * i], o.Fe0);  atomicAdd(&Fi[3 * i + 1], o.Fe1);  atomicAdd(&Fi[3 * i + 2], o.Fe2);
        atomicAdd(&Fi[3 * j], -o.Fe0); atomicAdd(&Fi[3 * j + 1], -o.Fe1); atomicAdd(&Fi[3 * j + 2], -o.Fe2);
        atomicAdd(&Mi[3 * i], o.Mi0);  atomicAdd(&Mi[3 * i + 1], o.Mi1);  atomicAdd(&Mi[3 * i + 2], o.Mi2);
        atomicAdd(&Mi[3 * j], o.Mj0);  atomicAdd(&Mi[3 * j + 1], o.Mj1);  atomicAdd(&Mi[3 * j + 2], o.Mj2);
        atomicAdd(&Fe[3 * i], o.E0);   atomicAdd(&Fe[3 * i + 1], o.E1);   atomicAdd(&Fe[3 * i + 2], o.E2);
        atomicAdd(&Fe[3 * j], o.E0);   atomicAdd(&Fe[3 * j + 1], o.E1);   atomicAdd(&Fe[3 * j + 2], o.E2);
        elem_reduce_tail(o, s_rkin2, s_e1, s_e2, s_Lsum, m_q, m_L);
    }
    blockAtomicAddD(s_rkin2, &sc->rkin2, smD);
    blockAtomicAddD(s_e1,    &sc->e1,    smD);
    blockAtomicAddD(s_e2,    &sc->e2,    smD);
    blockAtomicAddD(s_Lsum,  &sc->Lsum,  smD);
    blockAtomicMaxF(m_q, &sc->qmax_bits, smF);
    blockAtomicMaxF(m_L, &sc->Lmax_bits, smF);
}

__global__ __launch_bounds__(256) void node_soa(
    const float* __restrict__ Fi, const float* __restrict__ Mi, const float* __restrict__ Fe,
    const float* __restrict__ bc_disp, const float* __restrict__ bc_rot,
    Scal* sc, int n_nodes)
{
    __shared__ double smD[4];
    __shared__ unsigned smU[4];
    double sFe2 = 0.0, sF2 = 0.0, sMr2 = 0.0, sMp2 = 0.0;
    unsigned cd = 0, cr = 0, cp = 0;

    const int k = blockIdx.x * 256 + threadIdx.x;
    if (k < n_nodes) {
        const float bd = bc_disp[k], br = bc_rot[k];
        const bool free_d = bd < 0.5f;
        const bool free_r = br < 0.5f;
        const bool pin    = (bd > 0.5f) && free_r;
        if (free_d) {
            const float e0 = Fe[3 * k], e1 = Fe[3 * k + 1], e2 = Fe[3 * k + 2];
            const float f0 = Fi[3 * k] + e0, f1 = Fi[3 * k + 1] + e1, f2 = Fi[3 * k + 2] + e2;
            sFe2 += (double)(e0 * e0 + e1 * e1 + e2 * e2);
            sF2  += (double)(f0 * f0 + f1 * f1 + f2 * f2);
            cd++;
        }
        if (free_r | pin) {
            const float m0 = Mi[3 * k], m1 = Mi[3 * k + 1], m2 = Mi[3 * k + 2];
            const double mm = (double)(m0 * m0 + m1 * m1 + m2 * m2);
            if (free_r) { sMr2 += mm; cr++; }
            if (pin)    { sMp2 += mm; cp++; }
        }
    }
    blockAtomicAddD(sFe2, &sc->Fe2, smD);
    blockAtomicAddD(sF2,  &sc->F2,  smD);
    blockAtomicAddD(sMr2, &sc->Mr2, smD);
    blockAtomicAddD(sMp2, &sc->Mp2, smD);
    blockAtomicAddU(cd, &sc->cnt_d, smU);
    blockAtomicAddU(cr, &sc->cnt_r, smU);
    blockAtomicAddU(cp, &sc->cnt_p, smU);
}

__global__ void finalize(const Scal* sc, float* out, int n_elems)
{
    const double cnt_d = (double)max(sc->cnt_d, 1u);
    const double cnt_r = (double)max(sc->cnt_r, 1u);
    const double cnt_p = (double)max(sc->cnt_p, 1u);

    const double F_char = fmax(sqrt(sc->Fe2 / (cnt_d * 3.0)), 1.0);
    const double L_force = sc->F2 / (cnt_d * 3.0) / (F_char * F_char);

    const double qmax = fmax((double)__uint_as_float(sc->qmax_bits), 1.0);
    const double Lmax = (double)__uint_as_float(sc->Lmax_bits);
    const double M_char = fmax(qmax * Lmax * sc->Lsum / 8.0, 1.0);

    const double L_moment  = sc->Mr2 / (cnt_r * 3.0) / (M_char * M_char);
    const double L_neumann = sc->Mp2 / (cnt_p * 3.0) / (M_char * M_char);

    const double inv_ne = 1.0 / (double)n_elems;
    const double L_kin = sc->rkin2 * inv_ne;
    const double L_consist = sc->e1 * inv_ne + sc->e2 * inv_ne;

    out[0] = (float)(L_force + L_moment + L_neumann + 0.1 * L_kin + L_consist);
}

extern "C" void kernel_launch(void* const* d_in, const int* in_sizes, int n_in,
                              void* d_out, int out_size, void* d_ws, size_t ws_size,
                              hipStream_t stream)
{
    const float* pred     = (const float*)d_in[0];
    const float* grad_ux  = (const float*)d_in[1];
    const float* grad_uz  = (const float*)d_in[2];
    const float* grad_phi = (const float*)d_in[3];
    const float* prop_E   = (const float*)d_in[4];
    const float* prop_A   = (const float*)d_in[5];
    const float* prop_I22 = (const float*)d_in[6];
    const float* elemL    = (const float*)d_in[7];
    const float* dirs     = (const float*)d_in[8];
    const float* load     = (const float*)d_in[9];
    const float* bc_disp  = (const float*)d_in[10];
    const float* bc_rot   = (const float*)d_in[11];
    const int*   conn     = (const int*)d_in[12];

    const int n_elems = in_sizes[4];
    const int n_nodes = in_sizes[10];
    const int nblkN  = (n_nodes + 255) / 256;
    const int perBlk = 256 * ILP;
    const int nblkE4 = (n_elems + perBlk - 1) / perBlk;
    const int nblkN4 = (n_nodes + perBlk - 1) / perBlk;

    const size_t szPack = (size_t)n_nodes * 32;                  // 32MB fp16
    const size_t szPay  = (size_t)n_elems * 32;                  // 64MB fp16
    const size_t szHead = (size_t)n_nodes * sizeof(unsigned);    // 4MB
    const size_t szTail = 256;

    char* base = (char*)d_ws;

    if (ws_size >= szPack + szPay + szHead + szTail) {
        // ---- tier A: fp16 pack + linked-list (100MB, L3-resident) ----
        unsigned*     pack    = (unsigned*)base;     base += szPack;
        unsigned*     payload = (unsigned*)base;     base += szPay;
        unsigned int* head    = (unsigned int*)base; base += szHead;
        Scal*         sc      = (Scal*)base;

        hipMemsetAsync(sc, 0, sizeof(Scal), stream);

        pack_nodes<<<nblkN, 256, 0, stream>>>(
            pred, grad_ux, grad_uz, grad_phi, pack, head, n_nodes);
        elem_ll<true><<<nblkE4, 256, 0, stream>>>(
            pred, grad_ux, grad_uz, grad_phi, pack,
            prop_E, prop_A, prop_I22, elemL, dirs, load, conn,
            payload, head, sc, n_elems);
        node_ll<<<nblkN4, 256, 0, stream>>>(
            payload, head, bc_disp, bc_rot, sc, n_nodes);
        finalize<<<1, 1, 0, stream>>>(sc, (float*)d_out, n_elems);
    } else if (ws_size >= szPay + szHead + szTail) {
        // ---- tier B: fp16 linked-list without pack (68MB) ----
        unsigned*     payload = (unsigned*)base;     base += szPay;
        unsigned int* head    = (unsigned int*)base; base += szHead;
        Scal*         sc      = (Scal*)base;

        hipMemsetAsync(head, 0xFF, szHead, stream);
        hipMemsetAsync(sc, 0, sizeof(Scal), stream);

        elem_ll<false><<<nblkE4, 256, 0, stream>>>(
            pred, grad_ux, grad_uz, grad_phi, nullptr,
            prop_E, prop_A, prop_I22, elemL, dirs, load, conn,
            payload, head, sc, n_elems);
        node_ll<<<nblkN4, 256, 0, stream>>>(
            payload, head, bc_disp, bc_rot, sc, n_nodes);
        finalize<<<1, 1, 0, stream>>>(sc, (float*)d_out, n_elems);
    } else {
        // ---- tier C: SoA atomic fallback (36MB) ----
        float* Fi = (float*)d_ws;
        float* Mi = Fi + (size_t)3 * n_nodes;
        float* Fe = Mi + (size_t)3 * n_nodes;
        const size_t nodeBytes = (size_t)9 * n_nodes * sizeof(float);
        Scal* sc = (Scal*)((char*)d_ws + nodeBytes);

        hipMemsetAsync(d_ws, 0, nodeBytes + sizeof(Scal), stream);

        elem_soa<<<(n_elems + 255) / 256, 256, 0, stream>>>(
            pred, grad_ux, grad_uz, grad_phi,
            prop_E, prop_A, prop_I22, elemL, dirs, load, conn,
            Fi, Mi, Fe, sc, n_elems);
        node_soa<<<nblkN, 256, 0, stream>>>(
            Fi, Mi, Fe, bc_disp, bc_rot, sc, n_nodes);
        finalize<<<1, 1, 0, stream>>>(sc, (float*)d_out, n_elems);
    }
}